// Round 6
// baseline (789.417 us; speedup 1.0000x reference)
//
#include <hip/hip_runtime.h>
#include <stdint.h>

// ---------------------------------------------------------------------------
// Fused causal multi-head self-attention, bf16 MFMA pipeline.
// B=2, S=4096, D=1024, H=16, hd=64.  M = B*S = 8192.
//
// ws layout (bytes):
//   xb    @ 0         : 8192x1024 bf16   (16,777,216)
//   Wqkv  @ 16777216  : 3072x1024 bf16   ( 6,291,456)
//   Wob   @ 23068672  : 1024x1024 bf16   ( 2,097,152)
//   Q     @ 25165824  : [B,H,S,64] bf16  (16,777,216)   pre-scaled by log2e/8
//   K     @ 41943040  : [B,H,S,64] bf16  (16,777,216)
//   Vt    @ 58720256  : [B,H,64,S] bf16  (16,777,216)   (V transposed)
//   attn  @ 75497472  : [8192,1024] bf16 (16,777,216)
//
// Session notes:
//   R0 (paired 32-row chunks): PASSED 296us attn. 512 blocks = 2/CU —
//      occupancy GRID-limited (8 waves/CU); ~60-75% issue-slot stall.
//   R2+R5 (paired 16-row chunks): FAILED correctness BIT-IDENTICALLY
//      (absmax 468/23.4) under different launch_bounds and with/without
//      T13+T5 — deterministic semantic bug in that structure that five
//      derivation passes did not find. DO NOT retry blind.
//   R3 (K reg-prefetch): allocator pinned VGPR=128 and spilled the
//      prefetch buffer (WRITE_SIZE 21->479MB). Don't carry +32 VGPR of
//      live state across softmax+PV. T13 defer-max verified there.
//   R4 (T13 + setprio on R0): PASSED 290us, VGPR=128, no spills.
//   R6 (this): UNPAIRED 32-row chunks — same per-wave code as R4 with the
//      chunk-pair dimension deleted. 128 tasks/bh, grid (32,32) = 4
//      blocks/CU = 16 waves/CU. Total K-tile loads unchanged vs paired
//      (4160/bh either way); pairing only bought balance. Block bx holds
//      chunks {4bx..4bx+3} (equal within block; heavy blocks every 32nd
//      dispatch slot).
// ---------------------------------------------------------------------------

typedef unsigned short u16;
typedef __attribute__((ext_vector_type(8))) __bf16 bf16x8;
typedef __attribute__((ext_vector_type(4))) float floatx4;
typedef __attribute__((ext_vector_type(8))) unsigned short ushortx8;

__device__ __forceinline__ u16 f2b(float x) {        // RNE
  union { float f; unsigned int u; } v; v.f = x;
  unsigned int u = v.u;
  return (u16)((u + 0x7FFFu + ((u >> 16) & 1u)) >> 16);
}
__device__ __forceinline__ u16 f2b_fast(float x) {   // round-half-up (p >= 0 only)
  union { float f; unsigned int u; } v; v.f = x;
  return (u16)((v.u + 0x8000u) >> 16);
}

__device__ __forceinline__ bf16x8 ld8(const u16* p) {
  return __builtin_bit_cast(bf16x8, *(const ushortx8*)p);
}

#define MFMA16(a, b, c) __builtin_amdgcn_mfma_f32_16x16x32_bf16((a), (b), (c), 0, 0, 0)

#if __has_builtin(__builtin_amdgcn_exp2f)
#define EXP2(x) __builtin_amdgcn_exp2f(x)
#else
#define EXP2(x) exp2f(x)
#endif

// DPP cross-lane (VALU pipe, not LDS): butterfly reduce over 16-lane groups.
template <int CTRL>
__device__ __forceinline__ float dpp_mv(float x) {
  return __builtin_bit_cast(float,
      __builtin_amdgcn_mov_dpp(__builtin_bit_cast(int, x), CTRL, 0xF, 0xF, true));
}
__device__ __forceinline__ float rmax16(float x) {
  x = fmaxf(x, dpp_mv<0xB1>(x));   // quad_perm xor1
  x = fmaxf(x, dpp_mv<0x4E>(x));   // quad_perm xor2
  x = fmaxf(x, dpp_mv<0x141>(x));  // row_half_mirror (8-group)
  x = fmaxf(x, dpp_mv<0x140>(x));  // row_mirror (16-group)
  return x;
}
__device__ __forceinline__ float rsum16(float x) {
  x += dpp_mv<0xB1>(x);
  x += dpp_mv<0x4E>(x);
  x += dpp_mv<0x141>(x);
  x += dpp_mv<0x140>(x);
  return x;
}

// ---------------------------------------------------------------------------
__global__ void cvt_kernel(const float* __restrict__ src, u16* __restrict__ dst, int n) {
  int i = (blockIdx.x * 256 + threadIdx.x) * 8;
  if (i >= n) return;
  floatx4 a = *(const floatx4*)(src + i);
  floatx4 b = *(const floatx4*)(src + i + 4);
  ushortx8 o;
  o[0] = f2b(a[0]); o[1] = f2b(a[1]); o[2] = f2b(a[2]); o[3] = f2b(a[3]);
  o[4] = f2b(b[0]); o[5] = f2b(b[1]); o[6] = f2b(b[2]); o[7] = f2b(b[3]);
  *(ushortx8*)(dst + i) = o;
}

// ---------------------------------------------------------------------------
// GEMM  C[M,N] = A[M,K] * B[N,K]^T, K=1024. 128x128 tile, 4 waves 2x2.
// mode 0: QKV epilogue (Q pre-scaled by log2e/8; scatter Q,K; V transposed)
// mode 1: fp32 output epilogue
__global__ __launch_bounds__(256) void gemm_bt(
    const u16* __restrict__ A, const u16* __restrict__ B, int mode,
    u16* __restrict__ Qb, u16* __restrict__ Kb, u16* __restrict__ Vtb,
    float* __restrict__ out) {
  constexpr int K = 1024;
  constexpr int LDT = 40;
  __shared__ u16 At[128 * LDT];
  __shared__ u16 Bt[128 * LDT];
  int tid = threadIdx.x;
  int lane = tid & 63, w = tid >> 6;
  int quad = lane >> 4, l16 = lane & 15;
  int wr = w >> 1, wc = w & 1;

  floatx4 acc[4][4] = {};
  const u16* Ap = A + (size_t)(blockIdx.y * 128) * K;
  const u16* Bp = B + (size_t)(blockIdx.x * 128) * K;

  for (int k0 = 0; k0 < K; k0 += 32) {
    __syncthreads();
    for (int j = 0; j < 2; ++j) {
      int c = tid + 256 * j;
      int r = c >> 2, off = (c & 3) * 8;
      *(ushortx8*)(&At[r * LDT + off]) = *(const ushortx8*)(Ap + (size_t)r * K + k0 + off);
      *(ushortx8*)(&Bt[r * LDT + off]) = *(const ushortx8*)(Bp + (size_t)r * K + k0 + off);
    }
    __syncthreads();
    bf16x8 af[4], bfg[4];
    for (int i = 0; i < 4; ++i) af[i]  = ld8(&At[(wr * 64 + i * 16 + l16) * LDT + quad * 8]);
    for (int j = 0; j < 4; ++j) bfg[j] = ld8(&Bt[(wc * 64 + j * 16 + l16) * LDT + quad * 8]);
    for (int i = 0; i < 4; ++i)
      for (int j = 0; j < 4; ++j)
        acc[i][j] = MFMA16(af[i], bfg[j], acc[i][j]);
  }

  int rowbase = blockIdx.y * 128 + wr * 64 + quad * 4;
  int colbase = blockIdx.x * 128 + wc * 64 + l16;
  if (mode == 0) {
    const float qscale = 0.18033688f;  // (1/sqrt(64)) * log2(e), folded into Q
    for (int i = 0; i < 4; ++i)
      for (int j = 0; j < 4; ++j) {
        int gcol = colbase + j * 16;
        int which = gcol >> 10, within = gcol & 1023;
        int h = within >> 6, cc = within & 63;
        for (int r = 0; r < 4; ++r) {
          int grow = rowbase + i * 16 + r;
          int b = grow >> 12, s = grow & 4095;
          float av = acc[i][j][r];
          if (which == 0)      Qb[((size_t)((b * 16 + h) * 4096 + s)) * 64 + cc] = f2b(av * qscale);
          else if (which == 1) Kb[((size_t)((b * 16 + h) * 4096 + s)) * 64 + cc] = f2b(av);
          else                 Vtb[((size_t)((b * 16 + h) * 64 + cc)) * 4096 + s] = f2b(av);
        }
      }
  } else {
    for (int i = 0; i < 4; ++i)
      for (int r = 0; r < 4; ++r) {
        int grow = rowbase + i * 16 + r;
        float* op = out + (size_t)grow * 1024 + colbase;
        for (int j = 0; j < 4; ++j) op[j * 16] = acc[i][j][r];
      }
  }
}

// ---------------------------------------------------------------------------
// Causal flash attention, UNPAIRED 32-row chunks. Q pre-scaled by log2e/8.
// Q,K: [B,H,S,64], Vt: [B,H,64,S], out attn: [8192,1024].
// grid (32, 32), 4 waves/block. chunk = blockIdx.x*4 + w in [0,128):
//   rows 32*chunk .. +31, kv loop over [0, 32*chunk+32).
// Per-wave code is R4's verified body with the chunk-pair dimension removed
// (mi kept). 1024 blocks = 4 blocks/CU = 16 waves/CU vs R0/R4's 8.
// Includes verified T13 defer-max + T5 setprio.
__global__ __launch_bounds__(256, 2) void attn_kernel(
    const u16* __restrict__ Q, const u16* __restrict__ K,
    const u16* __restrict__ Vt, u16* __restrict__ attnb) {
  constexpr int LDP = 72;  // 64 + 8 pad
  __shared__ u16 Plds[4][32 * LDP];
  int tid = threadIdx.x;
  int lane = tid & 63, w = tid >> 6;
  int quad = lane >> 4, l16 = lane & 15;
  int bh = blockIdx.y;
  int chunk = blockIdx.x * 4 + w;  // 0..127
  int r0 = chunk * 32;
  const u16* Qh = Q  + (size_t)bh * 4096 * 64;
  const u16* Kh = K  + (size_t)bh * 4096 * 64;
  const u16* Vh = Vt + (size_t)bh * 64 * 4096;

  bf16x8 qf[2][2];             // [mi][p]
  floatx4 o[2][4] = {};        // [mi][h]
  float m[2][4], lp[2][4];
  for (int mi = 0; mi < 2; ++mi) {
    for (int p = 0; p < 2; ++p)
      qf[mi][p] = ld8(Qh + (size_t)(r0 + mi * 16 + l16) * 64 + p * 32 + quad * 8);
    for (int r = 0; r < 4; ++r) { m[mi][r] = -1e30f; lp[mi][r] = 0.f; }
  }

  int kvend = r0 + 32;
  for (int kv0 = 0; kv0 < kvend; kv0 += 64) {
    // ---- QK^T ----
    floatx4 s[2][4] = {};        // [mi][n]
    __builtin_amdgcn_s_setprio(1);
    for (int n = 0; n < 4; ++n) {
      const u16* kp = Kh + (size_t)(kv0 + n * 16 + l16) * 64;
      bf16x8 kf0 = ld8(kp + quad * 8);
      bf16x8 kf1 = ld8(kp + 32 + quad * 8);
      for (int mi = 0; mi < 2; ++mi) {
        s[mi][n] = MFMA16(qf[mi][0], kf0, s[mi][n]);
        s[mi][n] = MFMA16(qf[mi][1], kf1, s[mi][n]);
      }
    }
    __builtin_amdgcn_s_setprio(0);

    // ---- mask (diagonal/partial tile only) + online softmax + P store ----
    if (kv0 + 63 > r0) {
      for (int mi = 0; mi < 2; ++mi)
        for (int n = 0; n < 4; ++n) {
          int key = kv0 + n * 16 + l16;
          for (int r = 0; r < 4; ++r)
            if (key > r0 + mi * 16 + quad * 4 + r) s[mi][n][r] = -1e30f;
        }
    }
    u16* Pw = &Plds[w][0];
    float mn_[2][4], ls_[2][4];
    bool ch = false;
    for (int mi = 0; mi < 2; ++mi)
      for (int r = 0; r < 4; ++r) {
        float rm = fmaxf(fmaxf(s[mi][0][r], s[mi][1][r]),
                         fmaxf(s[mi][2][r], s[mi][3][r]));
        rm = rmax16(rm);
        float mo = m[mi][r];
        // T13 defer-max: only ratchet the running max when it jumps by >8
        // log2-units. P bounded by 2^8 (bf16-safe); verified in R3/R4.
        bool need = (rm > mo + 8.0f);
        float mx = need ? rm : mo;
        mn_[mi][r] = mx;
        ch |= need;
        float p0 = EXP2(s[mi][0][r] - mx);
        float p1 = EXP2(s[mi][1][r] - mx);
        float p2 = EXP2(s[mi][2][r] - mx);
        float p3 = EXP2(s[mi][3][r] - mx);
        ls_[mi][r] = (p0 + p1) + (p2 + p3);
        int rr = (mi * 16 + quad * 4 + r) * LDP + l16;
        Pw[rr]      = f2b_fast(p0);
        Pw[rr + 16] = f2b_fast(p1);
        Pw[rr + 32] = f2b_fast(p2);
        Pw[rr + 48] = f2b_fast(p3);
      }
    if (__any((int)ch)) {
      for (int mi = 0; mi < 2; ++mi)
        for (int r = 0; r < 4; ++r) {
          float al = EXP2(m[mi][r] - mn_[mi][r]);
          m[mi][r] = mn_[mi][r];
          lp[mi][r] = lp[mi][r] * al + ls_[mi][r];
          for (int h = 0; h < 4; ++h) o[mi][h][r] *= al;
        }
    } else {
      for (int mi = 0; mi < 2; ++mi)
        for (int r = 0; r < 4; ++r) lp[mi][r] += ls_[mi][r];
    }

    // ---- P (C-layout -> A-layout via per-wave LDS), PV ----
    bf16x8 pa[2][2];
    for (int mi = 0; mi < 2; ++mi)
      for (int p = 0; p < 2; ++p)
        pa[mi][p] = ld8(&Plds[w][(mi * 16 + l16) * LDP + p * 32 + quad * 8]);
    __builtin_amdgcn_s_setprio(1);
    for (int h = 0; h < 4; ++h) {
      const u16* vp = Vh + (size_t)(h * 16 + l16) * 4096 + kv0;
      bf16x8 vf0 = ld8(vp + quad * 8);
      bf16x8 vf1 = ld8(vp + 32 + quad * 8);
      for (int mi = 0; mi < 2; ++mi) {
        o[mi][h] = MFMA16(pa[mi][0], vf0, o[mi][h]);
        o[mi][h] = MFMA16(pa[mi][1], vf1, o[mi][h]);
      }
    }
    __builtin_amdgcn_s_setprio(0);
  }

  int b = bh >> 4, hh = bh & 15;
  for (int mi = 0; mi < 2; ++mi)
    for (int r = 0; r < 4; ++r) {
      float inv = 1.0f / rsum16(lp[mi][r]);
      int srow = r0 + mi * 16 + quad * 4 + r;
      size_t base = ((size_t)(b * 4096 + srow)) * 1024 + hh * 64;
      for (int h = 0; h < 4; ++h)
        attnb[base + h * 16 + l16] = f2b(o[mi][h][r] * inv);
    }
}

// ---------------------------------------------------------------------------
extern "C" void kernel_launch(void* const* d_in, const int* in_sizes, int n_in,
                              void* d_out, int out_size, void* d_ws, size_t ws_size,
                              hipStream_t stream) {
  const float* x  = (const float*)d_in[0];
  const float* Wq = (const float*)d_in[1];
  const float* Wk = (const float*)d_in[2];
  const float* Wv = (const float*)d_in[3];
  const float* Wo = (const float*)d_in[4];
  char* ws = (char*)d_ws;
  u16* xb    = (u16*)(ws + 0);
  u16* Wqkv  = (u16*)(ws + 16777216);
  u16* Wob   = (u16*)(ws + 23068672);
  u16* Qb    = (u16*)(ws + 25165824);
  u16* Kb    = (u16*)(ws + 41943040);
  u16* Vtb   = (u16*)(ws + 58720256);
  u16* attnb = (u16*)(ws + 75497472);

  cvt_kernel<<<4096, 256, 0, stream>>>(x, xb, 8388608);
  cvt_kernel<<<512, 256, 0, stream>>>(Wq, Wqkv, 1048576);
  cvt_kernel<<<512, 256, 0, stream>>>(Wk, Wqkv + 1048576, 1048576);
  cvt_kernel<<<512, 256, 0, stream>>>(Wv, Wqkv + 2097152, 1048576);
  cvt_kernel<<<512, 256, 0, stream>>>(Wo, Wob, 1048576);

  gemm_bt<<<dim3(24, 64), 256, 0, stream>>>(xb, Wqkv, 0, Qb, Kb, Vtb, nullptr);
  attn_kernel<<<dim3(32, 32), 256, 0, stream>>>(Qb, Kb, Vtb, attnb);
  gemm_bt<<<dim3(8, 64), 256, 0, stream>>>(attnb, Wob, 1, nullptr, nullptr, nullptr,
                                           (float*)d_out);
}

// Round 7
// 406.223 us; speedup vs baseline: 1.9433x; 1.9433x over previous
//
#include <hip/hip_runtime.h>
#include <stdint.h>

// ---------------------------------------------------------------------------
// Fused causal multi-head self-attention, bf16 MFMA pipeline.
// B=2, S=4096, D=1024, H=16, hd=64.  M = B*S = 8192.
//
// ws layout (bytes):
//   xb    @ 0         : 8192x1024 bf16   (16,777,216)
//   Wqkv  @ 16777216  : 3072x1024 bf16   ( 6,291,456)
//   Wob   @ 23068672  : 1024x1024 bf16   ( 2,097,152)
//   Q     @ 25165824  : [B,H,S,64] bf16  (16,777,216)   pre-scaled by log2e/8
//   K     @ 41943040  : [B,H,S,64] bf16  (16,777,216)
//   Vt    @ 58720256  : [B,H,64,S] bf16  (16,777,216)   (V transposed)
//   attn  @ 75497472  : [8192,1024] bf16 (16,777,216)
//
// Session notes:
//   R0/R4 (paired 32-row chunks [+T13+T5]): PASSED 296/290us. Stall-bound:
//      ~3.6K cy/trip exposed memory latency; each wave redundantly loads the
//      full 8KB K + 8KB V tile per trip.
//   R2+R5 (paired 16-row chunks): FAILED deterministically — unexplained
//      after 5 derivation passes. DO NOT retry blind.
//   R3 (K reg-prefetch): +32 VGPR live across body -> allocator pinned 128,
//      spilled to scratch (WRITE_SIZE 21->479MB). Tripwire: watch WRITE_SIZE.
//   R6 (unpaired chunks): PASSED 619us — per-CU imbalance trap: all blocks
//      resident at t=0, CU_i gets 4 same-weight blocks (grid.x stride ≡ 0
//      mod 32), no rebalance. Keep PAIRED (uniform waves).
//   R7 (this): cooperative LDS staging of K/V tiles (1 stage per block-trip
//      vs 4 redundant per-wave loads), XOR-swizzled; block-uniform kv loop +
//      wave-uniform predication; R4 compute body verbatim.
// ---------------------------------------------------------------------------

typedef unsigned short u16;
typedef __attribute__((ext_vector_type(8))) __bf16 bf16x8;
typedef __attribute__((ext_vector_type(4))) float floatx4;
typedef __attribute__((ext_vector_type(8))) unsigned short ushortx8;

__device__ __forceinline__ u16 f2b(float x) {        // RNE
  union { float f; unsigned int u; } v; v.f = x;
  unsigned int u = v.u;
  return (u16)((u + 0x7FFFu + ((u >> 16) & 1u)) >> 16);
}
__device__ __forceinline__ u16 f2b_fast(float x) {   // round-half-up (p >= 0 only)
  union { float f; unsigned int u; } v; v.f = x;
  return (u16)((v.u + 0x8000u) >> 16);
}

__device__ __forceinline__ bf16x8 ld8(const u16* p) {
  return __builtin_bit_cast(bf16x8, *(const ushortx8*)p);
}

#define MFMA16(a, b, c) __builtin_amdgcn_mfma_f32_16x16x32_bf16((a), (b), (c), 0, 0, 0)

#if __has_builtin(__builtin_amdgcn_exp2f)
#define EXP2(x) __builtin_amdgcn_exp2f(x)
#else
#define EXP2(x) exp2f(x)
#endif

// DPP cross-lane (VALU pipe, not LDS): butterfly reduce over 16-lane groups.
template <int CTRL>
__device__ __forceinline__ float dpp_mv(float x) {
  return __builtin_bit_cast(float,
      __builtin_amdgcn_mov_dpp(__builtin_bit_cast(int, x), CTRL, 0xF, 0xF, true));
}
__device__ __forceinline__ float rmax16(float x) {
  x = fmaxf(x, dpp_mv<0xB1>(x));   // quad_perm xor1
  x = fmaxf(x, dpp_mv<0x4E>(x));   // quad_perm xor2
  x = fmaxf(x, dpp_mv<0x141>(x));  // row_half_mirror (8-group)
  x = fmaxf(x, dpp_mv<0x140>(x));  // row_mirror (16-group)
  return x;
}
__device__ __forceinline__ float rsum16(float x) {
  x += dpp_mv<0xB1>(x);
  x += dpp_mv<0x4E>(x);
  x += dpp_mv<0x141>(x);
  x += dpp_mv<0x140>(x);
  return x;
}

// ---------------------------------------------------------------------------
__global__ void cvt_kernel(const float* __restrict__ src, u16* __restrict__ dst, int n) {
  int i = (blockIdx.x * 256 + threadIdx.x) * 8;
  if (i >= n) return;
  floatx4 a = *(const floatx4*)(src + i);
  floatx4 b = *(const floatx4*)(src + i + 4);
  ushortx8 o;
  o[0] = f2b(a[0]); o[1] = f2b(a[1]); o[2] = f2b(a[2]); o[3] = f2b(a[3]);
  o[4] = f2b(b[0]); o[5] = f2b(b[1]); o[6] = f2b(b[2]); o[7] = f2b(b[3]);
  *(ushortx8*)(dst + i) = o;
}

// ---------------------------------------------------------------------------
// GEMM  C[M,N] = A[M,K] * B[N,K]^T, K=1024. 128x128 tile, 4 waves 2x2.
// mode 0: QKV epilogue (Q pre-scaled by log2e/8; scatter Q,K; V transposed)
// mode 1: fp32 output epilogue
__global__ __launch_bounds__(256) void gemm_bt(
    const u16* __restrict__ A, const u16* __restrict__ B, int mode,
    u16* __restrict__ Qb, u16* __restrict__ Kb, u16* __restrict__ Vtb,
    float* __restrict__ out) {
  constexpr int K = 1024;
  constexpr int LDT = 40;
  __shared__ u16 At[128 * LDT];
  __shared__ u16 Bt[128 * LDT];
  int tid = threadIdx.x;
  int lane = tid & 63, w = tid >> 6;
  int quad = lane >> 4, l16 = lane & 15;
  int wr = w >> 1, wc = w & 1;

  floatx4 acc[4][4] = {};
  const u16* Ap = A + (size_t)(blockIdx.y * 128) * K;
  const u16* Bp = B + (size_t)(blockIdx.x * 128) * K;

  for (int k0 = 0; k0 < K; k0 += 32) {
    __syncthreads();
    for (int j = 0; j < 2; ++j) {
      int c = tid + 256 * j;
      int r = c >> 2, off = (c & 3) * 8;
      *(ushortx8*)(&At[r * LDT + off]) = *(const ushortx8*)(Ap + (size_t)r * K + k0 + off);
      *(ushortx8*)(&Bt[r * LDT + off]) = *(const ushortx8*)(Bp + (size_t)r * K + k0 + off);
    }
    __syncthreads();
    bf16x8 af[4], bfg[4];
    for (int i = 0; i < 4; ++i) af[i]  = ld8(&At[(wr * 64 + i * 16 + l16) * LDT + quad * 8]);
    for (int j = 0; j < 4; ++j) bfg[j] = ld8(&Bt[(wc * 64 + j * 16 + l16) * LDT + quad * 8]);
    for (int i = 0; i < 4; ++i)
      for (int j = 0; j < 4; ++j)
        acc[i][j] = MFMA16(af[i], bfg[j], acc[i][j]);
  }

  int rowbase = blockIdx.y * 128 + wr * 64 + quad * 4;
  int colbase = blockIdx.x * 128 + wc * 64 + l16;
  if (mode == 0) {
    const float qscale = 0.18033688f;  // (1/sqrt(64)) * log2(e), folded into Q
    for (int i = 0; i < 4; ++i)
      for (int j = 0; j < 4; ++j) {
        int gcol = colbase + j * 16;
        int which = gcol >> 10, within = gcol & 1023;
        int h = within >> 6, cc = within & 63;
        for (int r = 0; r < 4; ++r) {
          int grow = rowbase + i * 16 + r;
          int b = grow >> 12, s = grow & 4095;
          float av = acc[i][j][r];
          if (which == 0)      Qb[((size_t)((b * 16 + h) * 4096 + s)) * 64 + cc] = f2b(av * qscale);
          else if (which == 1) Kb[((size_t)((b * 16 + h) * 4096 + s)) * 64 + cc] = f2b(av);
          else                 Vtb[((size_t)((b * 16 + h) * 64 + cc)) * 4096 + s] = f2b(av);
        }
      }
  } else {
    for (int i = 0; i < 4; ++i)
      for (int r = 0; r < 4; ++r) {
        int grow = rowbase + i * 16 + r;
        float* op = out + (size_t)grow * 1024 + colbase;
        for (int j = 0; j < 4; ++j) op[j * 16] = acc[i][j][r];
      }
  }
}

// ---------------------------------------------------------------------------
// Causal flash attention, balanced paired chunks + cooperative K/V LDS staging.
// Q pre-scaled by log2e/8. Q,K: [B,H,S,64], Vt: [B,H,64,S], attn: [8192,1024].
// grid (16, 32), 4 waves/block. task = bx*4+w in [0,64):
//   chunk lo = task      (rows 32*task .. +31),  active while kv0 < 32*task+32
//   chunk hi = 127-task  (rows 4064-32*task .. +31)
// Block loops kv0 over [0, kvend_blk), kvend_blk = 4096-128*bx (block-uniform);
// each trip the whole block stages the 64x64 K tile and 64x64 V-slice into
// LDS once (16KB coalesced, XOR-swizzled cols: col8 ^= row&7 — G4 recipe,
// 2-way reads = free), then waves compute predicated on kv0 < kvend_h.
// Compute body verbatim R4 (T13 defer-max + T5 setprio), fragments from LDS.
__global__ __launch_bounds__(256, 2) void attn_kernel(
    const u16* __restrict__ Q, const u16* __restrict__ K,
    const u16* __restrict__ Vt, u16* __restrict__ attnb) {
  constexpr int LDP = 72;  // 64 + 8 pad
  __shared__ u16 Plds[4][2][32 * LDP];
  __shared__ u16 Klds[64 * 64];
  __shared__ u16 Vlds[64 * 64];
  int tid = threadIdx.x;
  int lane = tid & 63, w = tid >> 6;
  int quad = lane >> 4, l16 = lane & 15;
  int bh = blockIdx.y;
  int task = blockIdx.x * 4 + w;  // 0..63
  int r0[2];
  r0[0] = task * 32;          // lo chunk
  r0[1] = 4064 - task * 32;   // hi chunk = (127-task)*32
  const u16* Qh = Q  + (size_t)bh * 4096 * 64;
  const u16* Kh = K  + (size_t)bh * 4096 * 64;
  const u16* Vh = Vt + (size_t)bh * 64 * 4096;

  // staging assignment: 512 16B-chunks per tile, 256 threads -> rows sr, sr+32
  int sr = tid >> 3;                        // 0..31
  int c8 = tid & 7;                         // 16B chunk within 128B row
  int wcol = (c8 * 8) ^ ((sr & 7) << 3);    // swizzled col (u16); (sr+32)&7==sr&7
  int swz = (l16 & 7) << 3;                 // read-side swizzle

  bf16x8 qf[2][2][2];          // [chunk][mi][p]
  floatx4 o[2][2][4] = {};     // [chunk][mi][h]
  float m[2][2][4], lp[2][2][4];
  for (int c = 0; c < 2; ++c)
    for (int mi = 0; mi < 2; ++mi) {
      for (int p = 0; p < 2; ++p)
        qf[c][mi][p] = ld8(Qh + (size_t)(r0[c] + mi * 16 + l16) * 64 + p * 32 + quad * 8);
      for (int r = 0; r < 4; ++r) { m[c][mi][r] = -1e30f; lp[c][mi][r] = 0.f; }
    }

  int kvend_l = r0[0] + 32;
  int kvend_h = r0[1] + 32;
  int kvend_blk = 4096 - blockIdx.x * 128;  // = kvend_h of wave w=0 (block max)

  for (int kv0 = 0; kv0 < kvend_blk; kv0 += 64) {
    // ---- cooperative stage: K[kv0..+64)[0..64), Vt[0..64)[kv0..+64) ----
    __syncthreads();  // previous trip's LDS reads complete
    {
      ushortx8 k1 = *(const ushortx8*)(Kh + (size_t)(kv0 + sr) * 64 + c8 * 8);
      ushortx8 k2 = *(const ushortx8*)(Kh + (size_t)(kv0 + sr + 32) * 64 + c8 * 8);
      ushortx8 v1 = *(const ushortx8*)(Vh + (size_t)sr * 4096 + kv0 + c8 * 8);
      ushortx8 v2 = *(const ushortx8*)(Vh + (size_t)(sr + 32) * 4096 + kv0 + c8 * 8);
      *(ushortx8*)&Klds[sr * 64 + wcol] = k1;
      *(ushortx8*)&Klds[(sr + 32) * 64 + wcol] = k2;
      *(ushortx8*)&Vlds[sr * 64 + wcol] = v1;
      *(ushortx8*)&Vlds[(sr + 32) * 64 + wcol] = v2;
    }
    __syncthreads();  // tile visible

    bool doHi = (kv0 < kvend_h);  // wave-uniform
    bool doLo = (kv0 < kvend_l);  // wave-uniform; doLo implies doHi
    if (doHi) {
      // ---- QK^T for both chunks, shared K fragments (from LDS) ----
      floatx4 s[2][2][4] = {};     // [chunk][mi][n]
      __builtin_amdgcn_s_setprio(1);
      for (int n = 0; n < 4; ++n) {
        const u16* kb = &Klds[(n * 16 + l16) * 64];
        bf16x8 kf0 = ld8(kb + ((quad * 8) ^ swz));
        bf16x8 kf1 = ld8(kb + (((quad * 8) + 32) ^ swz));
        for (int mi = 0; mi < 2; ++mi) {
          s[1][mi][n] = MFMA16(qf[1][mi][0], kf0, s[1][mi][n]);
          s[1][mi][n] = MFMA16(qf[1][mi][1], kf1, s[1][mi][n]);
        }
        if (doLo)
          for (int mi = 0; mi < 2; ++mi) {
            s[0][mi][n] = MFMA16(qf[0][mi][0], kf0, s[0][mi][n]);
            s[0][mi][n] = MFMA16(qf[0][mi][1], kf1, s[0][mi][n]);
          }
      }
      __builtin_amdgcn_s_setprio(0);

      // ---- per-chunk mask + online softmax + P store ----
      for (int c = 0; c < 2; ++c) {
        if (c == 0 && !doLo) continue;
        if (kv0 + 63 > r0[c]) {  // diagonal/partial tile only
          for (int mi = 0; mi < 2; ++mi)
            for (int n = 0; n < 4; ++n) {
              int key = kv0 + n * 16 + l16;
              for (int r = 0; r < 4; ++r)
                if (key > r0[c] + mi * 16 + quad * 4 + r) s[c][mi][n][r] = -1e30f;
            }
        }
        u16* Pw = &Plds[w][c][0];
        float mn_[2][4], ls_[2][4];
        bool ch = false;
        for (int mi = 0; mi < 2; ++mi)
          for (int r = 0; r < 4; ++r) {
            float rm = fmaxf(fmaxf(s[c][mi][0][r], s[c][mi][1][r]),
                             fmaxf(s[c][mi][2][r], s[c][mi][3][r]));
            rm = rmax16(rm);
            float mo = m[c][mi][r];
            // T13 defer-max (verified R3/R4): ratchet only on >8 log2-unit jump.
            bool need = (rm > mo + 8.0f);
            float mx = need ? rm : mo;
            mn_[mi][r] = mx;
            ch |= need;
            float p0 = EXP2(s[c][mi][0][r] - mx);
            float p1 = EXP2(s[c][mi][1][r] - mx);
            float p2 = EXP2(s[c][mi][2][r] - mx);
            float p3 = EXP2(s[c][mi][3][r] - mx);
            ls_[mi][r] = (p0 + p1) + (p2 + p3);
            int rr = (mi * 16 + quad * 4 + r) * LDP + l16;
            Pw[rr]      = f2b_fast(p0);
            Pw[rr + 16] = f2b_fast(p1);
            Pw[rr + 32] = f2b_fast(p2);
            Pw[rr + 48] = f2b_fast(p3);
          }
        if (__any((int)ch)) {
          for (int mi = 0; mi < 2; ++mi)
            for (int r = 0; r < 4; ++r) {
              float al = EXP2(m[c][mi][r] - mn_[mi][r]);
              m[c][mi][r] = mn_[mi][r];
              lp[c][mi][r] = lp[c][mi][r] * al + ls_[mi][r];
              for (int h = 0; h < 4; ++h) o[c][mi][h][r] *= al;
            }
        } else {
          for (int mi = 0; mi < 2; ++mi)
            for (int r = 0; r < 4; ++r) lp[c][mi][r] += ls_[mi][r];
        }
      }

      // ---- P (C-layout -> A-layout via per-wave LDS), PV with shared V ----
      bf16x8 pa[2][2][2];
      for (int c = 0; c < 2; ++c) {
        if (c == 0 && !doLo) continue;
        for (int mi = 0; mi < 2; ++mi)
          for (int p = 0; p < 2; ++p)
            pa[c][mi][p] = ld8(&Plds[w][c][(mi * 16 + l16) * LDP + p * 32 + quad * 8]);
      }
      __builtin_amdgcn_s_setprio(1);
      for (int h = 0; h < 4; ++h) {
        const u16* vb = &Vlds[(h * 16 + l16) * 64];
        bf16x8 vf0 = ld8(vb + ((quad * 8) ^ swz));
        bf16x8 vf1 = ld8(vb + (((quad * 8) + 32) ^ swz));
        for (int mi = 0; mi < 2; ++mi) {
          o[1][mi][h] = MFMA16(pa[1][mi][0], vf0, o[1][mi][h]);
          o[1][mi][h] = MFMA16(pa[1][mi][1], vf1, o[1][mi][h]);
        }
        if (doLo)
          for (int mi = 0; mi < 2; ++mi) {
            o[0][mi][h] = MFMA16(pa[0][mi][0], vf0, o[0][mi][h]);
            o[0][mi][h] = MFMA16(pa[0][mi][1], vf1, o[0][mi][h]);
          }
      }
      __builtin_amdgcn_s_setprio(0);
    }
  }

  int b = bh >> 4, hh = bh & 15;
  for (int c = 0; c < 2; ++c)
    for (int mi = 0; mi < 2; ++mi)
      for (int r = 0; r < 4; ++r) {
        float inv = 1.0f / rsum16(lp[c][mi][r]);
        int srow = r0[c] + mi * 16 + quad * 4 + r;
        size_t base = ((size_t)(b * 4096 + srow)) * 1024 + hh * 64;
        for (int h = 0; h < 4; ++h)
          attnb[base + h * 16 + l16] = f2b(o[c][mi][h][r] * inv);
      }
}

// ---------------------------------------------------------------------------
extern "C" void kernel_launch(void* const* d_in, const int* in_sizes, int n_in,
                              void* d_out, int out_size, void* d_ws, size_t ws_size,
                              hipStream_t stream) {
  const float* x  = (const float*)d_in[0];
  const float* Wq = (const float*)d_in[1];
  const float* Wk = (const float*)d_in[2];
  const float* Wv = (const float*)d_in[3];
  const float* Wo = (const float*)d_in[4];
  char* ws = (char*)d_ws;
  u16* xb    = (u16*)(ws + 0);
  u16* Wqkv  = (u16*)(ws + 16777216);
  u16* Wob   = (u16*)(ws + 23068672);
  u16* Qb    = (u16*)(ws + 25165824);
  u16* Kb    = (u16*)(ws + 41943040);
  u16* Vtb   = (u16*)(ws + 58720256);
  u16* attnb = (u16*)(ws + 75497472);

  cvt_kernel<<<4096, 256, 0, stream>>>(x, xb, 8388608);
  cvt_kernel<<<512, 256, 0, stream>>>(Wq, Wqkv, 1048576);
  cvt_kernel<<<512, 256, 0, stream>>>(Wk, Wqkv + 1048576, 1048576);
  cvt_kernel<<<512, 256, 0, stream>>>(Wv, Wqkv + 2097152, 1048576);
  cvt_kernel<<<512, 256, 0, stream>>>(Wo, Wob, 1048576);

  gemm_bt<<<dim3(24, 64), 256, 0, stream>>>(xb, Wqkv, 0, Qb, Kb, Vtb, nullptr);
  attn_kernel<<<dim3(16, 32), 256, 0, stream>>>(Qb, Kb, Vtb, attnb);
  gemm_bt<<<dim3(8, 64), 256, 0, stream>>>(attnb, Wob, 1, nullptr, nullptr, nullptr,
                                           (float*)d_out);
}

// Round 8
// 402.770 us; speedup vs baseline: 1.9600x; 1.0086x over previous
//
#include <hip/hip_runtime.h>
#include <stdint.h>

// ---------------------------------------------------------------------------
// Fused causal multi-head self-attention, bf16 MFMA pipeline.
// B=2, S=4096, D=1024, H=16, hd=64.  M = B*S = 8192.
//
// ws layout (bytes):
//   xb    @ 0         : 8192x1024 bf16   (16,777,216)
//   Wqkv  @ 16777216  : 3072x1024 bf16   ( 6,291,456)
//   Wob   @ 23068672  : 1024x1024 bf16   ( 2,097,152)
//   Q     @ 25165824  : [B,H,S,64] bf16  (16,777,216)   pre-scaled by log2e/8
//   K     @ 41943040  : [B,H,S,64] bf16  (16,777,216)
//   Vt    @ 58720256  : [B,H,64,S] bf16  (16,777,216)   (V transposed)
//   attn  @ 75497472  : [8192,1024] bf16 (16,777,216)
//
// Session notes:
//   R0/R4: paired 32-row chunks, per-wave K/V loads. 296/290us.
//   R2+R5 (16-row chunks): FAILED deterministically. DO NOT retry blind.
//   R3: +32 VGPR live across body -> pinned 128, scratch spill
//      (WRITE_SIZE 21->479MB). Tripwire: WRITE_SIZE must stay ~25MB.
//   R6 (unpaired): 619us — per-CU imbalance: CU gets same-bx blocks.
//   R7: coop LDS staging of K/V, XOR-swizzle: PASSED 190.6us
//      (MfmaUtil 15.2, VALUBusy 49.7). Matched prediction.
//   R8 (this): (a) balance remap — by>=16 flips bx -> per-CU pair weight
//      const 98 trip-units (was up to 128); (b) double-buffered
//      global_load_lds staging (linear dest + inverse-swz source, rule #21),
//      1 barrier/trip, loads overlap compute; (c) Plds shrunk to 1 chunk
//      (softmax->PV per chunk) to fit 51200B LDS.
// ---------------------------------------------------------------------------

typedef unsigned short u16;
typedef __attribute__((ext_vector_type(8))) __bf16 bf16x8;
typedef __attribute__((ext_vector_type(4))) float floatx4;
typedef __attribute__((ext_vector_type(8))) unsigned short ushortx8;

__device__ __forceinline__ u16 f2b(float x) {        // RNE
  union { float f; unsigned int u; } v; v.f = x;
  unsigned int u = v.u;
  return (u16)((u + 0x7FFFu + ((u >> 16) & 1u)) >> 16);
}
__device__ __forceinline__ u16 f2b_fast(float x) {   // round-half-up (p >= 0 only)
  union { float f; unsigned int u; } v; v.f = x;
  return (u16)((v.u + 0x8000u) >> 16);
}

__device__ __forceinline__ bf16x8 ld8(const u16* p) {
  return __builtin_bit_cast(bf16x8, *(const ushortx8*)p);
}

#define MFMA16(a, b, c) __builtin_amdgcn_mfma_f32_16x16x32_bf16((a), (b), (c), 0, 0, 0)

#if __has_builtin(__builtin_amdgcn_exp2f)
#define EXP2(x) __builtin_amdgcn_exp2f(x)
#else
#define EXP2(x) exp2f(x)
#endif

// DPP cross-lane (VALU pipe, not LDS): butterfly reduce over 16-lane groups.
template <int CTRL>
__device__ __forceinline__ float dpp_mv(float x) {
  return __builtin_bit_cast(float,
      __builtin_amdgcn_mov_dpp(__builtin_bit_cast(int, x), CTRL, 0xF, 0xF, true));
}
__device__ __forceinline__ float rmax16(float x) {
  x = fmaxf(x, dpp_mv<0xB1>(x));   // quad_perm xor1
  x = fmaxf(x, dpp_mv<0x4E>(x));   // quad_perm xor2
  x = fmaxf(x, dpp_mv<0x141>(x));  // row_half_mirror (8-group)
  x = fmaxf(x, dpp_mv<0x140>(x));  // row_mirror (16-group)
  return x;
}
__device__ __forceinline__ float rsum16(float x) {
  x += dpp_mv<0xB1>(x);
  x += dpp_mv<0x4E>(x);
  x += dpp_mv<0x141>(x);
  x += dpp_mv<0x140>(x);
  return x;
}

// ---------------------------------------------------------------------------
__global__ void cvt_kernel(const float* __restrict__ src, u16* __restrict__ dst, int n) {
  int i = (blockIdx.x * 256 + threadIdx.x) * 8;
  if (i >= n) return;
  floatx4 a = *(const floatx4*)(src + i);
  floatx4 b = *(const floatx4*)(src + i + 4);
  ushortx8 o;
  o[0] = f2b(a[0]); o[1] = f2b(a[1]); o[2] = f2b(a[2]); o[3] = f2b(a[3]);
  o[4] = f2b(b[0]); o[5] = f2b(b[1]); o[6] = f2b(b[2]); o[7] = f2b(b[3]);
  *(ushortx8*)(dst + i) = o;
}

// ---------------------------------------------------------------------------
// GEMM  C[M,N] = A[M,K] * B[N,K]^T, K=1024. 128x128 tile, 4 waves 2x2.
// mode 0: QKV epilogue (Q pre-scaled by log2e/8; scatter Q,K; V transposed)
// mode 1: fp32 output epilogue
__global__ __launch_bounds__(256) void gemm_bt(
    const u16* __restrict__ A, const u16* __restrict__ B, int mode,
    u16* __restrict__ Qb, u16* __restrict__ Kb, u16* __restrict__ Vtb,
    float* __restrict__ out) {
  constexpr int K = 1024;
  constexpr int LDT = 40;
  __shared__ u16 At[128 * LDT];
  __shared__ u16 Bt[128 * LDT];
  int tid = threadIdx.x;
  int lane = tid & 63, w = tid >> 6;
  int quad = lane >> 4, l16 = lane & 15;
  int wr = w >> 1, wc = w & 1;

  floatx4 acc[4][4] = {};
  const u16* Ap = A + (size_t)(blockIdx.y * 128) * K;
  const u16* Bp = B + (size_t)(blockIdx.x * 128) * K;

  for (int k0 = 0; k0 < K; k0 += 32) {
    __syncthreads();
    for (int j = 0; j < 2; ++j) {
      int c = tid + 256 * j;
      int r = c >> 2, off = (c & 3) * 8;
      *(ushortx8*)(&At[r * LDT + off]) = *(const ushortx8*)(Ap + (size_t)r * K + k0 + off);
      *(ushortx8*)(&Bt[r * LDT + off]) = *(const ushortx8*)(Bp + (size_t)r * K + k0 + off);
    }
    __syncthreads();
    bf16x8 af[4], bfg[4];
    for (int i = 0; i < 4; ++i) af[i]  = ld8(&At[(wr * 64 + i * 16 + l16) * LDT + quad * 8]);
    for (int j = 0; j < 4; ++j) bfg[j] = ld8(&Bt[(wc * 64 + j * 16 + l16) * LDT + quad * 8]);
    for (int i = 0; i < 4; ++i)
      for (int j = 0; j < 4; ++j)
        acc[i][j] = MFMA16(af[i], bfg[j], acc[i][j]);
  }

  int rowbase = blockIdx.y * 128 + wr * 64 + quad * 4;
  int colbase = blockIdx.x * 128 + wc * 64 + l16;
  if (mode == 0) {
    const float qscale = 0.18033688f;  // (1/sqrt(64)) * log2(e), folded into Q
    for (int i = 0; i < 4; ++i)
      for (int j = 0; j < 4; ++j) {
        int gcol = colbase + j * 16;
        int which = gcol >> 10, within = gcol & 1023;
        int h = within >> 6, cc = within & 63;
        for (int r = 0; r < 4; ++r) {
          int grow = rowbase + i * 16 + r;
          int b = grow >> 12, s = grow & 4095;
          float av = acc[i][j][r];
          if (which == 0)      Qb[((size_t)((b * 16 + h) * 4096 + s)) * 64 + cc] = f2b(av * qscale);
          else if (which == 1) Kb[((size_t)((b * 16 + h) * 4096 + s)) * 64 + cc] = f2b(av);
          else                 Vtb[((size_t)((b * 16 + h) * 64 + cc)) * 4096 + s] = f2b(av);
        }
      }
  } else {
    for (int i = 0; i < 4; ++i)
      for (int r = 0; r < 4; ++r) {
        int grow = rowbase + i * 16 + r;
        float* op = out + (size_t)grow * 1024 + colbase;
        for (int j = 0; j < 4; ++j) op[j * 16] = acc[i][j][r];
      }
  }
}

// ---------------------------------------------------------------------------
// Causal flash attention, paired chunks + double-buffered global_load_lds
// K/V staging. Q pre-scaled by log2e/8. Q,K: [B,H,S,64], Vt: [B,H,64,S].
// grid (16, 32), 4 waves/block. bx = balance-remapped blockIdx.x:
//   by<16: bx = blockIdx.x ; by>=16: bx = 15-blockIdx.x  (bijective; per-CU
//   block pair {j, j+256} then has complementary weights, 98 trip-units const).
// task = bx*4+w in [0,64): chunk lo = task (rows 32*task..+31, active while
// kv0 < 32*task+32); chunk hi = 127-task (rows 4064-32*task..+31).
// Per trip: stage tile t+1 into buf cur^1 via global_load_lds (linear LDS
// dest, inverse-XOR-swizzled per-lane global source — rule #21), compute
// tile t from buf cur, ONE barrier (its vmcnt drain lands after compute).
// Per-chunk softmax->PV (P buffer 1-chunk, wave-private). T13 + T5 kept.
__global__ __launch_bounds__(256, 2) void attn_kernel(
    const u16* __restrict__ Q, const u16* __restrict__ K,
    const u16* __restrict__ Vt, u16* __restrict__ attnb) {
  constexpr int LDP = 72;  // 64 + 8 pad
  __shared__ u16 Plds[4][32 * LDP];
  __shared__ u16 Klds[2][4096];   // [buf][64 rows x 64 cols], XOR-swizzled cols
  __shared__ u16 Vlds[2][4096];
  int tid = threadIdx.x;
  int lane = tid & 63, w = tid >> 6;
  int quad = lane >> 4, l16 = lane & 15;
  int bh = blockIdx.y;
  int bx = (bh < 16) ? blockIdx.x : 15 - blockIdx.x;  // balance remap
  int task = bx * 4 + w;  // 0..63
  int r0[2];
  r0[0] = task * 32;          // lo chunk
  r0[1] = 4064 - task * 32;   // hi chunk = (127-task)*32
  const u16* Qh = Q  + (size_t)bh * 4096 * 64;
  const u16* Kh = K  + (size_t)bh * 4096 * 64;
  const u16* Vh = Vt + (size_t)bh * 64 * 4096;

  // Staging geometry: tile = 64 rows x 128B; segment s = rows 8s..8s+7 (1KB).
  // Wave w stages segments {w, w+4} of K and of V: one global_load_lds(16B)
  // each, LDS dest = wave-uniform segment base + lane*16 (linear).
  // Lane l covers LDS (row 8s + (l>>3), chunk l&7); inverse swizzle puts the
  // global source at chunk (l&7) ^ (l>>3)  [row&7 == l>>3 since 8s%8==0].
  int r8 = lane >> 3;                 // row within segment
  int sc8 = (lane & 7) ^ r8;          // inverse-swizzled source 16B-chunk
  int koffA = (w * 8 + r8) * 64 + sc8 * 8;          // u16 offsets
  int koffB = ((w + 4) * 8 + r8) * 64 + sc8 * 8;
  int voffA = (w * 8 + r8) * 4096 + sc8 * 8;
  int voffB = ((w + 4) * 8 + r8) * 4096 + sc8 * 8;
  auto stage = [&](int buf, int kv) {
    const u16* kbase = Kh + (size_t)kv * 64;
    const u16* vbase = Vh + kv;
    __builtin_amdgcn_global_load_lds(
        (const __attribute__((address_space(1))) void*)(kbase + koffA),
        (__attribute__((address_space(3))) void*)(&Klds[buf][w * 512]), 16, 0, 0);
    __builtin_amdgcn_global_load_lds(
        (const __attribute__((address_space(1))) void*)(kbase + koffB),
        (__attribute__((address_space(3))) void*)(&Klds[buf][(w + 4) * 512]), 16, 0, 0);
    __builtin_amdgcn_global_load_lds(
        (const __attribute__((address_space(1))) void*)(vbase + voffA),
        (__attribute__((address_space(3))) void*)(&Vlds[buf][w * 512]), 16, 0, 0);
    __builtin_amdgcn_global_load_lds(
        (const __attribute__((address_space(1))) void*)(vbase + voffB),
        (__attribute__((address_space(3))) void*)(&Vlds[buf][(w + 4) * 512]), 16, 0, 0);
  };

  int swz = (l16 & 7) << 3;  // read-side swizzle (XOR on u16 offset)

  bf16x8 qf[2][2][2];          // [chunk][mi][p]
  floatx4 o[2][2][4] = {};     // [chunk][mi][h]
  float m[2][2][4], lp[2][2][4];
  for (int c = 0; c < 2; ++c)
    for (int mi = 0; mi < 2; ++mi) {
      for (int p = 0; p < 2; ++p)
        qf[c][mi][p] = ld8(Qh + (size_t)(r0[c] + mi * 16 + l16) * 64 + p * 32 + quad * 8);
      for (int r = 0; r < 4; ++r) { m[c][mi][r] = -1e30f; lp[c][mi][r] = 0.f; }
    }

  int kvend_l = r0[0] + 32;
  int kvend_h = r0[1] + 32;
  int kvend_blk = 4096 - bx * 128;  // block-uniform trip bound

  stage(0, 0);
  __syncthreads();
  int cur = 0;

  for (int kv0 = 0; kv0 < kvend_blk; kv0 += 64) {
    int kvn = kv0 + 64;
    if (kvn < kvend_blk) stage(cur ^ 1, kvn);  // overlap with compute below

    bool doHi = (kv0 < kvend_h);  // wave-uniform
    bool doLo = (kv0 < kvend_l);  // wave-uniform; implies doHi
    if (doHi) {
      // ---- QK^T for both chunks, shared K fragments (from LDS) ----
      floatx4 s[2][2][4] = {};     // [chunk][mi][n]
      __builtin_amdgcn_s_setprio(1);
      for (int n = 0; n < 4; ++n) {
        const u16* kb = &Klds[cur][(n * 16 + l16) * 64];
        bf16x8 kf0 = ld8(kb + ((quad * 8) ^ swz));
        bf16x8 kf1 = ld8(kb + (((quad * 8) + 32) ^ swz));
        for (int mi = 0; mi < 2; ++mi) {
          s[1][mi][n] = MFMA16(qf[1][mi][0], kf0, s[1][mi][n]);
          s[1][mi][n] = MFMA16(qf[1][mi][1], kf1, s[1][mi][n]);
        }
        if (doLo)
          for (int mi = 0; mi < 2; ++mi) {
            s[0][mi][n] = MFMA16(qf[0][mi][0], kf0, s[0][mi][n]);
            s[0][mi][n] = MFMA16(qf[0][mi][1], kf1, s[0][mi][n]);
          }
      }
      __builtin_amdgcn_s_setprio(0);

      // ---- per chunk: mask + online softmax + P store -> PV ----
      for (int c = 1; c >= 0; --c) {
        if (c == 0 && !doLo) continue;
        if (kv0 + 63 > r0[c]) {  // diagonal/partial tile only
          for (int mi = 0; mi < 2; ++mi)
            for (int n = 0; n < 4; ++n) {
              int key = kv0 + n * 16 + l16;
              for (int r = 0; r < 4; ++r)
                if (key > r0[c] + mi * 16 + quad * 4 + r) s[c][mi][n][r] = -1e30f;
            }
        }
        u16* Pw = &Plds[w][0];
        float mn_[2][4], ls_[2][4];
        bool ch = false;
        for (int mi = 0; mi < 2; ++mi)
          for (int r = 0; r < 4; ++r) {
            float rm = fmaxf(fmaxf(s[c][mi][0][r], s[c][mi][1][r]),
                             fmaxf(s[c][mi][2][r], s[c][mi][3][r]));
            rm = rmax16(rm);
            float mo = m[c][mi][r];
            // T13 defer-max (verified R3/R4): ratchet only on >8 log2-unit jump.
            bool need = (rm > mo + 8.0f);
            float mx = need ? rm : mo;
            mn_[mi][r] = mx;
            ch |= need;
            float p0 = EXP2(s[c][mi][0][r] - mx);
            float p1 = EXP2(s[c][mi][1][r] - mx);
            float p2 = EXP2(s[c][mi][2][r] - mx);
            float p3 = EXP2(s[c][mi][3][r] - mx);
            ls_[mi][r] = (p0 + p1) + (p2 + p3);
            int rr = (mi * 16 + quad * 4 + r) * LDP + l16;
            Pw[rr]      = f2b_fast(p0);
            Pw[rr + 16] = f2b_fast(p1);
            Pw[rr + 32] = f2b_fast(p2);
            Pw[rr + 48] = f2b_fast(p3);
          }
        if (__any((int)ch)) {
          for (int mi = 0; mi < 2; ++mi)
            for (int r = 0; r < 4; ++r) {
              float al = EXP2(m[c][mi][r] - mn_[mi][r]);
              m[c][mi][r] = mn_[mi][r];
              lp[c][mi][r] = lp[c][mi][r] * al + ls_[mi][r];
              for (int h = 0; h < 4; ++h) o[c][mi][h][r] *= al;
            }
        } else {
          for (int mi = 0; mi < 2; ++mi)
            for (int r = 0; r < 4; ++r) lp[c][mi][r] += ls_[mi][r];
        }

        // P (C-layout -> A-layout via per-wave LDS), then PV for this chunk
        bf16x8 pa[2][2];
        for (int mi = 0; mi < 2; ++mi)
          for (int p = 0; p < 2; ++p)
            pa[mi][p] = ld8(&Plds[w][(mi * 16 + l16) * LDP + p * 32 + quad * 8]);
        __builtin_amdgcn_s_setprio(1);
        for (int h = 0; h < 4; ++h) {
          const u16* vb = &Vlds[cur][(h * 16 + l16) * 64];
          bf16x8 vf0 = ld8(vb + ((quad * 8) ^ swz));
          bf16x8 vf1 = ld8(vb + (((quad * 8) + 32) ^ swz));
          for (int mi = 0; mi < 2; ++mi) {
            o[c][mi][h] = MFMA16(pa[mi][0], vf0, o[c][mi][h]);
            o[c][mi][h] = MFMA16(pa[mi][1], vf1, o[c][mi][h]);
          }
        }
        __builtin_amdgcn_s_setprio(0);
      }
    }

    __syncthreads();  // drains staged loads (overlapped) + protects buf reuse
    cur ^= 1;
  }

  int b = bh >> 4, hh = bh & 15;
  for (int c = 0; c < 2; ++c)
    for (int mi = 0; mi < 2; ++mi)
      for (int r = 0; r < 4; ++r) {
        float inv = 1.0f / rsum16(lp[c][mi][r]);
        int srow = r0[c] + mi * 16 + quad * 4 + r;
        size_t base = ((size_t)(b * 4096 + srow)) * 1024 + hh * 64;
        for (int h = 0; h < 4; ++h)
          attnb[base + h * 16 + l16] = f2b(o[c][mi][h][r] * inv);
      }
}

// ---------------------------------------------------------------------------
extern "C" void kernel_launch(void* const* d_in, const int* in_sizes, int n_in,
                              void* d_out, int out_size, void* d_ws, size_t ws_size,
                              hipStream_t stream) {
  const float* x  = (const float*)d_in[0];
  const float* Wq = (const float*)d_in[1];
  const float* Wk = (const float*)d_in[2];
  const float* Wv = (const float*)d_in[3];
  const float* Wo = (const float*)d_in[4];
  char* ws = (char*)d_ws;
  u16* xb    = (u16*)(ws + 0);
  u16* Wqkv  = (u16*)(ws + 16777216);
  u16* Wob   = (u16*)(ws + 23068672);
  u16* Qb    = (u16*)(ws + 25165824);
  u16* Kb    = (u16*)(ws + 41943040);
  u16* Vtb   = (u16*)(ws + 58720256);
  u16* attnb = (u16*)(ws + 75497472);

  cvt_kernel<<<4096, 256, 0, stream>>>(x, xb, 8388608);
  cvt_kernel<<<512, 256, 0, stream>>>(Wq, Wqkv, 1048576);
  cvt_kernel<<<512, 256, 0, stream>>>(Wk, Wqkv + 1048576, 1048576);
  cvt_kernel<<<512, 256, 0, stream>>>(Wv, Wqkv + 2097152, 1048576);
  cvt_kernel<<<512, 256, 0, stream>>>(Wo, Wob, 1048576);

  gemm_bt<<<dim3(24, 64), 256, 0, stream>>>(xb, Wqkv, 0, Qb, Kb, Vtb, nullptr);
  attn_kernel<<<dim3(16, 32), 256, 0, stream>>>(Qb, Kb, Vtb, attnb);
  gemm_bt<<<dim3(8, 64), 256, 0, stream>>>(attnb, Wob, 1, nullptr, nullptr, nullptr,
                                           (float*)d_out);
}